// Round 2
// baseline (547.204 us; speedup 1.0000x reference)
//
#include <hip/hip_runtime.h>

// Problem: prediction [M=16,K=16,N=16,B=2048,C=10] fp32, label [B] int.
// out = mean over all slices of (argmax_c pred == label[b]).
// NSLICE = 8388608 slices of 10 contiguous floats (40 B). Memory-bound:
// 320 MiB read once -> ~53 us at 6.3 TB/s.
//
// Each thread handles a PAIR of slices (80 B = 5 float4). To keep global
// loads coalesced, each wave stages its 320 contiguous float4 (5 KB) into
// LDS with lane-contiguous addressing (1 KB/instruction), then reads back
// per-pair fragments from LDS (conflict-free: bank = (20*lane+4i)%32).

#define NSLICE (16 * 16 * 16 * 2048)
#define BATCH 2048
#define NCLS 10

__global__ void eval_init(float* out) {
    if (threadIdx.x == 0 && blockIdx.x == 0) out[0] = 0.0f;
}

__global__ __launch_bounds__(256) void eval_acc(const float4* __restrict__ pred4,
                                                const int* __restrict__ label,
                                                float* __restrict__ out) {
    __shared__ float4 sh[1280];  // 4 waves * 320 float4 = 20 KB
    __shared__ int wsum[4];

    const int w = threadIdx.x >> 6;
    const int lane = threadIdx.x & 63;

    // Block covers 256 pairs = 1280 float4; wave w covers float4 [w*320, w*320+320)
    const size_t blockF4 = (size_t)blockIdx.x * 1280 + (size_t)w * 320;
    float4* lw = &sh[w * 320];

#pragma unroll
    for (int i = 0; i < 5; ++i)
        lw[i * 64 + lane] = pred4[blockF4 + (size_t)i * 64 + lane];  // coalesced 1KB/instr

    __syncthreads();

    float f[20];
#pragma unroll
    for (int i = 0; i < 5; ++i) {
        const float4 v = lw[lane * 5 + i];
        f[i * 4 + 0] = v.x;
        f[i * 4 + 1] = v.y;
        f[i * 4 + 2] = v.z;
        f[i * 4 + 3] = v.w;
    }

    // This lane's pair index; slices 2p, 2p+1 ; b = slice & 2047 ; b1 = b0+1
    const int pair = blockIdx.x * 256 + w * 64 + lane;
    const int b0 = (2 * pair) & (BATCH - 1);
    const int lab0 = label[b0];
    const int lab1 = label[b0 + 1];

    int bi0 = 0;
    float m0 = f[0];
#pragma unroll
    for (int j = 1; j < NCLS; ++j)
        if (f[j] > m0) { m0 = f[j]; bi0 = j; }  // first-max wins, matches jnp
    int bi1 = 0;
    float m1 = f[NCLS];
#pragma unroll
    for (int j = 1; j < NCLS; ++j)
        if (f[NCLS + j] > m1) { m1 = f[NCLS + j]; bi1 = j; }

    int local = (bi0 == lab0) + (bi1 == lab1);

    // wave-64 reduction
#pragma unroll
    for (int off = 32; off > 0; off >>= 1) local += __shfl_down(local, off, 64);

    if (lane == 0) wsum[w] = local;
    __syncthreads();
    if (threadIdx.x == 0) {
        const float s = (float)(wsum[0] + wsum[1] + wsum[2] + wsum[3]);
        // every contribution is k*2^-23 with running total <= 1.0 -> exact fp32,
        // order-independent, so float atomics are deterministic here
        atomicAdd(out, s * (1.0f / (float)NSLICE));
    }
}

extern "C" void kernel_launch(void* const* d_in, const int* in_sizes, int n_in,
                              void* d_out, int out_size, void* d_ws, size_t ws_size,
                              hipStream_t stream) {
    const float4* pred4 = (const float4*)d_in[0];
    const int* label = (const int*)d_in[1];
    float* out = (float*)d_out;

    eval_init<<<1, 64, 0, stream>>>(out);

    // NSLICE/2 = 4194304 pairs; 256 pairs/block -> 16384 blocks, exact fit
    eval_acc<<<16384, 256, 0, stream>>>(pred4, label, out);
}

// Round 3
// 440.493 us; speedup vs baseline: 1.2423x; 1.2423x over previous
//
#include <hip/hip_runtime.h>

// Problem: prediction [M=16,K=16,N=16,B=2048,C=10] fp32, label [B] int.
// out = mean over all slices of (argmax_c pred == label[b]).
// NSLICE = 8388608 slices of 10 contiguous floats (40 B). 320 MiB read once.
//
// R2 finding: 16384 same-address device atomics serialized at ~14 ns each
// (~223 us), independent of memory level. R3: zero atomics — per-block
// partials to d_ws, tiny second kernel reduces.
//
// eval_acc: 2048 blocks x 256 threads, grid-strided. Each iteration a wave
// stages 320 contiguous float4 (5 KB) into LDS coalesced (1 KB/instr), then
// each lane reads its pair's 5 float4 back (bank (20*lane+4i)%32 -> conflict
// free, verified SQ_LDS_BANK_CONFLICT=0 in R2).

#define NSLICE (16 * 16 * 16 * 2048)
#define BATCH 2048
#define NCLS 10
#define NBLOCKS 2048
#define NPAIRS (NSLICE / 2)          // 4194304
#define CHUNKS (NPAIRS / 256)        // 16384 chunks of 256 pairs
#define ITERS (CHUNKS / NBLOCKS)     // 8

__global__ __launch_bounds__(256) void eval_acc(const float4* __restrict__ pred4,
                                                const int* __restrict__ label,
                                                int* __restrict__ partial) {
    __shared__ float4 sh[1280];  // 4 waves * 320 float4 = 20 KB
    __shared__ int wsum[4];

    const int w = threadIdx.x >> 6;
    const int lane = threadIdx.x & 63;

    int local = 0;

#pragma unroll
    for (int it = 0; it < ITERS; ++it) {
        const int chunk = it * NBLOCKS + blockIdx.x;  // block-stride for L2 spread
        // wave w stages float4 [chunk*1280 + w*320, +320)
        const size_t baseF4 = (size_t)chunk * 1280 + (size_t)w * 320;
        float4* lw = &sh[w * 320];

#pragma unroll
        for (int i = 0; i < 5; ++i)
            lw[i * 64 + lane] = pred4[baseF4 + (size_t)i * 64 + lane];  // coalesced 1KB/instr

        __syncthreads();

        float f[20];
#pragma unroll
        for (int i = 0; i < 5; ++i) {
            const float4 v = lw[lane * 5 + i];
            f[i * 4 + 0] = v.x;
            f[i * 4 + 1] = v.y;
            f[i * 4 + 2] = v.z;
            f[i * 4 + 3] = v.w;
        }

        // this lane's pair; slices 2p,2p+1 ; b = slice & 2047 ; b1 = b0+1
        const int pair = chunk * 256 + w * 64 + lane;
        const int b0 = (2 * pair) & (BATCH - 1);
        const int lab0 = label[b0];
        const int lab1 = label[b0 + 1];

        int bi0 = 0;
        float m0 = f[0];
#pragma unroll
        for (int j = 1; j < NCLS; ++j)
            if (f[j] > m0) { m0 = f[j]; bi0 = j; }  // first-max wins, matches jnp
        int bi1 = 0;
        float m1 = f[NCLS];
#pragma unroll
        for (int j = 1; j < NCLS; ++j)
            if (f[NCLS + j] > m1) { m1 = f[NCLS + j]; bi1 = j; }

        local += (bi0 == lab0) + (bi1 == lab1);

        __syncthreads();  // protect LDS before next iteration overwrites
    }

    // wave-64 reduction, then cross-wave via LDS; ONE plain store per block
#pragma unroll
    for (int off = 32; off > 0; off >>= 1) local += __shfl_down(local, off, 64);

    if (lane == 0) wsum[w] = local;
    __syncthreads();
    if (threadIdx.x == 0)
        partial[blockIdx.x] = wsum[0] + wsum[1] + wsum[2] + wsum[3];
}

__global__ __launch_bounds__(256) void eval_fin(const int* __restrict__ partial,
                                                float* __restrict__ out) {
    __shared__ int wsum[4];
    const int w = threadIdx.x >> 6;
    const int lane = threadIdx.x & 63;

    int s = 0;
#pragma unroll
    for (int i = 0; i < NBLOCKS / 256; ++i)  // 8 values per thread
        s += partial[i * 256 + threadIdx.x];

#pragma unroll
    for (int off = 32; off > 0; off >>= 1) s += __shfl_down(s, off, 64);

    if (lane == 0) wsum[w] = s;
    __syncthreads();
    if (threadIdx.x == 0) {
        const int total = wsum[0] + wsum[1] + wsum[2] + wsum[3];
        // total <= 2^23 exactly representable; /2^23 exact
        out[0] = (float)total * (1.0f / (float)NSLICE);
    }
}

extern "C" void kernel_launch(void* const* d_in, const int* in_sizes, int n_in,
                              void* d_out, int out_size, void* d_ws, size_t ws_size,
                              hipStream_t stream) {
    const float4* pred4 = (const float4*)d_in[0];
    const int* label = (const int*)d_in[1];
    int* partial = (int*)d_ws;  // 2048 ints; fully overwritten before read
    float* out = (float*)d_out;

    eval_acc<<<NBLOCKS, 256, 0, stream>>>(pred4, label, partial);
    eval_fin<<<1, 256, 0, stream>>>(partial, out);
}

// Round 4
// 430.627 us; speedup vs baseline: 1.2707x; 1.0229x over previous
//
#include <hip/hip_runtime.h>

// Problem: prediction [M=16,K=16,N=16,B=2048,C=10] fp32, label [B] int.
// out = mean over all slices of (argmax_c pred == label[b]).
// NSLICE = 8388608 slices of 10 contiguous floats (40 B). 336 MB read once.
//
// R2/R3 findings: same-address atomics were the 223 us floor (R2 replay ran
// 223 us even with FETCH~0 -> not memory-bound). R3 (LDS-staged, per-block
// partials) ~= 120 us inferred. R4 A/B: drop LDS staging + barriers, direct
// 80B-strided float4 loads (5 per thread = one slice-pair), zero atomics.
// Budget: ~40 L1-line txns/load-instr but total txn time ~21 us; BW floor
// ~30-55 us (input half L3-resident after harness restore).

#define NSLICE (16 * 16 * 16 * 2048)
#define BATCH 2048
#define NCLS 10
#define NBLOCKS 16384  // NSLICE/2 pairs / 256 threads, exact

__global__ __launch_bounds__(256) void eval_acc(const float4* __restrict__ pred4,
                                                const int* __restrict__ label,
                                                int* __restrict__ partial) {
    const int pair = blockIdx.x * 256 + threadIdx.x;  // exact grid, no bounds check
    const size_t base = 5ull * (size_t)pair;

    // 5 independent loads -> full MLP, no barriers, no LDS round-trip
    const float4 v0 = pred4[base + 0];
    const float4 v1 = pred4[base + 1];
    const float4 v2 = pred4[base + 2];
    const float4 v3 = pred4[base + 3];
    const float4 v4 = pred4[base + 4];

    const int b0 = (2 * pair) & (BATCH - 1);  // slice 2p even -> b1 = b0+1
    const int lab0 = label[b0];
    const int lab1 = label[b0 + 1];

    float f[20];
    f[0] = v0.x;  f[1] = v0.y;  f[2] = v0.z;  f[3] = v0.w;
    f[4] = v1.x;  f[5] = v1.y;  f[6] = v1.z;  f[7] = v1.w;
    f[8] = v2.x;  f[9] = v2.y;  f[10] = v2.z; f[11] = v2.w;
    f[12] = v3.x; f[13] = v3.y; f[14] = v3.z; f[15] = v3.w;
    f[16] = v4.x; f[17] = v4.y; f[18] = v4.z; f[19] = v4.w;

    int bi0 = 0;
    float m0 = f[0];
#pragma unroll
    for (int j = 1; j < NCLS; ++j)
        if (f[j] > m0) { m0 = f[j]; bi0 = j; }  // first-max wins, matches jnp
    int bi1 = 0;
    float m1 = f[NCLS];
#pragma unroll
    for (int j = 1; j < NCLS; ++j)
        if (f[NCLS + j] > m1) { m1 = f[NCLS + j]; bi1 = j; }

    int local = (bi0 == lab0) + (bi1 == lab1);

#pragma unroll
    for (int off = 32; off > 0; off >>= 1) local += __shfl_down(local, off, 64);

    __shared__ int wsum[4];
    const int w = threadIdx.x >> 6;
    if ((threadIdx.x & 63) == 0) wsum[w] = local;
    __syncthreads();
    if (threadIdx.x == 0)
        partial[blockIdx.x] = wsum[0] + wsum[1] + wsum[2] + wsum[3];
}

__global__ __launch_bounds__(1024) void eval_fin(const int* __restrict__ partial,
                                                 float* __restrict__ out) {
    __shared__ int wsum[16];
    const int w = threadIdx.x >> 6;
    const int lane = threadIdx.x & 63;

    int s = 0;
#pragma unroll
    for (int i = 0; i < NBLOCKS / 1024; ++i)  // 16 per thread, coalesced
        s += partial[i * 1024 + threadIdx.x];

#pragma unroll
    for (int off = 32; off > 0; off >>= 1) s += __shfl_down(s, off, 64);

    if (lane == 0) wsum[w] = s;
    __syncthreads();
    if (threadIdx.x == 0) {
        int total = 0;
#pragma unroll
        for (int i = 0; i < 16; ++i) total += wsum[i];
        // total <= 2^23 exactly representable; /2^23 exact
        out[0] = (float)total * (1.0f / (float)NSLICE);
    }
}

extern "C" void kernel_launch(void* const* d_in, const int* in_sizes, int n_in,
                              void* d_out, int out_size, void* d_ws, size_t ws_size,
                              hipStream_t stream) {
    const float4* pred4 = (const float4*)d_in[0];
    const int* label = (const int*)d_in[1];
    int* partial = (int*)d_ws;  // 16384 ints, fully overwritten before read
    float* out = (float*)d_out;

    eval_acc<<<NBLOCKS, 256, 0, stream>>>(pred4, label, partial);
    eval_fin<<<1, 1024, 0, stream>>>(partial, out);
}